// Round 7
// baseline (26.022 us; speedup 1.0000x reference)
//
#include <hip/hip_runtime.h>
#include <math.h>

#define BM    64
#define ASTR  528                  // A row stride in LDS (16B-aligned -> b128 a-reads)
#define BSTR  520                  // B row stride in LDS (8B-aligned -> b64 b-reads)
#define AOFF  0
#define BOFF  (BM * ASTR)          // 33792
#define POFF  (BOFF + BM * BSTR)   // 67072: partials
#define PSTR  72
#define LDSZ  (POFF + 1024 * PSTR) // 140800 B

typedef _Float16 h2 __attribute__((ext_vector_type(2)));
__device__ __forceinline__ h2 u2h(unsigned u) { return __builtin_bit_cast(h2, u); }
__device__ __forceinline__ unsigned h2u(h2 h) { return __builtin_bit_cast(unsigned, h); }

// ---- prepass: sigmoid -> fp16 rows (8B units) + row sums of rounded values ----
__global__ __launch_bounds__(256)
void prepass(const float* __restrict__ x1, const float* __restrict__ x2,
             uint2* __restrict__ Ah, uint2* __restrict__ Bh,
             float* __restrict__ rs) {
    const int wid = threadIdx.x >> 6, lane = threadIdx.x & 63;
    const int r = blockIdx.x * 4 + wid;            // 0..2047
    const bool isA = (r < 1024);
    const int row = isA ? r : (r - 1024);
    const float* src = (isA ? x1 : x2) + (size_t)row * 256;

    float4 g = *(const float4*)(src + 4 * lane);
    float4 s;
    s.x = 1.0f / (1.0f + __expf(-g.x));
    s.y = 1.0f / (1.0f + __expf(-g.y));
    s.z = 1.0f / (1.0f + __expf(-g.z));
    s.w = 1.0f / (1.0f + __expf(-g.w));
    h2 lo, hi;
    lo.x = (_Float16)s.x; lo.y = (_Float16)s.y;
    hi.x = (_Float16)s.z; hi.y = (_Float16)s.w;

    (isA ? Ah : Bh)[(size_t)row * 64 + lane] = make_uint2(h2u(lo), h2u(hi));

    float sum = ((float)lo.x + (float)lo.y) + ((float)hi.x + (float)hi.y);
    #pragma unroll
    for (int k = 32; k >= 1; k >>= 1)
        sum += __shfl_xor(sum, k, 64);
    if (lane == 0) rs[r] = sum;
}

// ---- main: copy-only staging, R6 inner loop (4x4 microtile, D quarters) ----
__global__ __launch_bounds__(1024, 4)
void jaccard_main(const uint2* __restrict__ Ah, const uint2* __restrict__ Bh,
                  const float* __restrict__ rs, float* __restrict__ out) {
    extern __shared__ char lds[];
    char* ATile = lds + AOFF;
    char* BTile = lds + BOFF;
    char* Part  = lds + POFF;

    const int bi = blockIdx.x, bj = blockIdx.y;
    const int tid = threadIdx.x;

    // ---- staging: pure fp16 copy, 64 KB total, b64 units, no math ----
    // A: 64 rows x 64 units; B: same. 4096 units each over 1024 threads.
    #pragma unroll
    for (int k = 0; k < 4; ++k) {
        const int flat = tid + 1024 * k;           // 0..4095
        const int row = flat >> 6, c8 = flat & 63;
        uint2 va = Ah[(size_t)(bi * BM + row) * 64 + c8];
        *(uint2*)(ATile + row * ASTR + c8 * 8) = va;
        uint2 vb = Bh[(size_t)(bj * BM + row) * 64 + c8];
        *(uint2*)(BTile + row * BSTR + c8 * 8) = vb;
    }
    __syncthreads();

    // ---- inner loop: identical to R6 ----
    const int s  = tid & 255;
    const int q  = tid >> 8;       // D-quarter: chunks [8q, 8q+8)
    const int tx = s & 15;
    const int ty = s >> 4;

    const char* ab = ATile + ty * ASTR + q * 128;
    const char* bb = BTile + tx * BSTR + q * 128;

    h2 acc[4][4] = {};
    #pragma unroll
    for (int cc = 0; cc < 8; ++cc) {
        uint4 av[4];
        #pragma unroll
        for (int m = 0; m < 4; ++m)
            av[m] = *(const uint4*)(ab + m * (16 * ASTR) + cc * 16);
        uint2 bl[4], bh[4];
        #pragma unroll
        for (int n = 0; n < 4; ++n) {
            bl[n] = *(const uint2*)(bb + n * (16 * BSTR) + cc * 16);
            bh[n] = *(const uint2*)(bb + n * (16 * BSTR) + cc * 16 + 8);
        }
        #pragma unroll
        for (int m = 0; m < 4; ++m) {
            h2 a0 = u2h(av[m].x), a1 = u2h(av[m].y), a2 = u2h(av[m].z), a3 = u2h(av[m].w);
            #pragma unroll
            for (int n = 0; n < 4; ++n) {
                h2 m0 = __builtin_elementwise_min(a0, u2h(bl[n].x));
                h2 m1 = __builtin_elementwise_min(a1, u2h(bl[n].y));
                h2 m2 = __builtin_elementwise_min(a2, u2h(bh[n].x));
                h2 m3 = __builtin_elementwise_min(a3, u2h(bh[n].y));
                acc[m][n] += (m0 + m1) + (m2 + m3);
            }
        }
    }

    char* pw = Part + (size_t)(q * 256 + s) * PSTR;
    #pragma unroll
    for (int m = 0; m < 4; ++m) {
        *(uint2*)(pw + m * 16)     = make_uint2(h2u(acc[m][0]), h2u(acc[m][1]));
        *(uint2*)(pw + m * 16 + 8) = make_uint2(h2u(acc[m][2]), h2u(acc[m][3]));
    }
    __syncthreads();

    float in0 = 0.f, in1 = 0.f, in2 = 0.f, in3 = 0.f;
    #pragma unroll
    for (int qq = 0; qq < 4; ++qq) {
        const char* rp = Part + (size_t)(qq * 256 + s) * PSTR + q * 16;
        uint2 lo = *(const uint2*)rp;
        uint2 hi = *(const uint2*)(rp + 8);
        h2 p0 = u2h(lo.x), p1 = u2h(lo.y), p2 = u2h(hi.x), p3 = u2h(hi.y);
        in0 += (float)p0.x + (float)p0.y;
        in1 += (float)p1.x + (float)p1.y;
        in2 += (float)p2.x + (float)p2.y;
        in3 += (float)p3.x + (float)p3.y;
    }

    const int i  = bi * 64 + ty + 16 * q;
    const int j0 = bj * 64 + tx;

    const float sa  = rs[i];
    const float sb0 = rs[1024 + j0];
    const float sb1 = rs[1024 + j0 + 16];
    const float sb2 = rs[1024 + j0 + 32];
    const float sb3 = rs[1024 + j0 + 48];

    const float v0 = in0 / (sa + sb0 - in0);
    const float v1 = in1 / (sa + sb1 - in1);
    const float v2 = in2 / (sa + sb2 - in2);
    const float v3 = in3 / (sa + sb3 - in3);

    float* outT = out + (size_t)1024 * 1024;
    out[(size_t)i * 1024 + j0]      = v0;
    out[(size_t)i * 1024 + j0 + 16] = v1;
    out[(size_t)i * 1024 + j0 + 32] = v2;
    out[(size_t)i * 1024 + j0 + 48] = v3;
    outT[(size_t)j0        * 1024 + i] = v0;
    outT[(size_t)(j0 + 16) * 1024 + i] = v1;
    outT[(size_t)(j0 + 32) * 1024 + i] = v2;
    outT[(size_t)(j0 + 48) * 1024 + i] = v3;
}

extern "C" void kernel_launch(void* const* d_in, const int* in_sizes, int n_in,
                              void* d_out, int out_size, void* d_ws, size_t ws_size,
                              hipStream_t stream) {
    const float* x1 = (const float*)d_in[0];
    const float* x2 = (const float*)d_in[1];
    float* out = (float*)d_out;

    uint2* Ah = (uint2*)d_ws;                       // 1024*64 uint2 = 512 KB
    uint2* Bh = Ah + (size_t)1024 * 64;             // 512 KB
    float* rs = (float*)(Bh + (size_t)1024 * 64);   // 2048 floats

    hipFuncSetAttribute((const void*)jaccard_main,
                        hipFuncAttributeMaxDynamicSharedMemorySize, LDSZ);

    prepass<<<512, 256, 0, stream>>>(x1, x2, Ah, Bh, rs);
    jaccard_main<<<dim3(16, 16), 1024, LDSZ, stream>>>(Ah, Bh, rs, out);
}

// Round 8
// 24.432 us; speedup vs baseline: 1.0651x; 1.0651x over previous
//
#include <hip/hip_runtime.h>
#include <math.h>

#define BM    64
#define ASTR  528                  // A row stride in LDS (16B-aligned -> b128 a-reads)
#define BSTR  520                  // B row stride in LDS (8B-aligned -> b64 b-reads)
#define AOFF  0
#define BOFF  (BM * ASTR)          // 33792
#define POFF  (BOFF + BM * BSTR)   // 67072: partials
#define PSTR  72
#define LDSZ  (POFF + 1024 * PSTR) // 140800 B

typedef _Float16 h2 __attribute__((ext_vector_type(2)));
__device__ __forceinline__ h2 u2h(unsigned u) { return __builtin_bit_cast(h2, u); }
__device__ __forceinline__ unsigned h2u(h2 h) { return __builtin_bit_cast(unsigned, h); }

// Guaranteed-packed fp16 ops (1 instruction each, VOP3P)
__device__ __forceinline__ unsigned pkmin(unsigned a, unsigned b) {
    unsigned d;
    asm("v_pk_min_f16 %0, %1, %2" : "=v"(d) : "v"(a), "v"(b));
    return d;
}
__device__ __forceinline__ unsigned pkadd(unsigned a, unsigned b) {
    unsigned d;
    asm("v_pk_add_f16 %0, %1, %2" : "=v"(d) : "v"(a), "v"(b));
    return d;
}

// ---- prepass: sigmoid -> fp16 rows (8B units) + row sums of rounded values ----
__global__ __launch_bounds__(256)
void prepass(const float* __restrict__ x1, const float* __restrict__ x2,
             uint2* __restrict__ Ah, uint2* __restrict__ Bh,
             float* __restrict__ rs) {
    const int wid = threadIdx.x >> 6, lane = threadIdx.x & 63;
    const int r = blockIdx.x * 4 + wid;            // 0..2047
    const bool isA = (r < 1024);
    const int row = isA ? r : (r - 1024);
    const float* src = (isA ? x1 : x2) + (size_t)row * 256;

    float4 g = *(const float4*)(src + 4 * lane);
    float4 s;
    s.x = 1.0f / (1.0f + __expf(-g.x));
    s.y = 1.0f / (1.0f + __expf(-g.y));
    s.z = 1.0f / (1.0f + __expf(-g.z));
    s.w = 1.0f / (1.0f + __expf(-g.w));
    h2 lo, hi;
    lo.x = (_Float16)s.x; lo.y = (_Float16)s.y;
    hi.x = (_Float16)s.z; hi.y = (_Float16)s.w;

    (isA ? Ah : Bh)[(size_t)row * 64 + lane] = make_uint2(h2u(lo), h2u(hi));

    float sum = ((float)lo.x + (float)lo.y) + ((float)hi.x + (float)hi.y);
    #pragma unroll
    for (int k = 32; k >= 1; k >>= 1)
        sum += __shfl_xor(sum, k, 64);
    if (lane == 0) rs[r] = sum;
}

// ---- main: copy-only staging, 4x4 microtile, D quarters, asm-packed fp16 ----
__global__ __launch_bounds__(1024, 4)
void jaccard_main(const uint2* __restrict__ Ah, const uint2* __restrict__ Bh,
                  const float* __restrict__ rs, float* __restrict__ out) {
    extern __shared__ char lds[];
    char* ATile = lds + AOFF;
    char* BTile = lds + BOFF;
    char* Part  = lds + POFF;

    const int bi = blockIdx.x, bj = blockIdx.y;
    const int tid = threadIdx.x;

    // ---- staging: pure fp16 copy, 64 KB total, b64 units, no math ----
    #pragma unroll
    for (int k = 0; k < 4; ++k) {
        const int flat = tid + 1024 * k;           // 0..4095
        const int row = flat >> 6, c8 = flat & 63;
        uint2 va = Ah[(size_t)(bi * BM + row) * 64 + c8];
        *(uint2*)(ATile + row * ASTR + c8 * 8) = va;
        uint2 vb = Bh[(size_t)(bj * BM + row) * 64 + c8];
        *(uint2*)(BTile + row * BSTR + c8 * 8) = vb;
    }
    __syncthreads();

    const int s  = tid & 255;
    const int q  = tid >> 8;       // D-quarter: chunks [8q, 8q+8)
    const int tx = s & 15;
    const int ty = s >> 4;

    const char* ab = ATile + ty * ASTR + q * 128;
    const char* bb = BTile + tx * BSTR + q * 128;

    unsigned acc[4][4] = {};       // packed h2 accumulators (0x0 == {0h,0h})
    #pragma unroll
    for (int cc = 0; cc < 8; ++cc) {
        uint4 av[4];
        #pragma unroll
        for (int m = 0; m < 4; ++m)
            av[m] = *(const uint4*)(ab + m * (16 * ASTR) + cc * 16);
        uint4 bv[4];
        #pragma unroll
        for (int n = 0; n < 4; ++n) {
            uint2 lo = *(const uint2*)(bb + n * (16 * BSTR) + cc * 16);
            uint2 hi = *(const uint2*)(bb + n * (16 * BSTR) + cc * 16 + 8);
            bv[n] = make_uint4(lo.x, lo.y, hi.x, hi.y);
        }
        #pragma unroll
        for (int m = 0; m < 4; ++m) {
            #pragma unroll
            for (int n = 0; n < 4; ++n) {
                unsigned t0 = pkmin(av[m].x, bv[n].x);
                unsigned t1 = pkmin(av[m].y, bv[n].y);
                unsigned t2 = pkmin(av[m].z, bv[n].z);
                unsigned t3 = pkmin(av[m].w, bv[n].w);
                acc[m][n] = pkadd(acc[m][n], pkadd(pkadd(t0, t1), pkadd(t2, t3)));
            }
        }
    }

    char* pw = Part + (size_t)(q * 256 + s) * PSTR;
    #pragma unroll
    for (int m = 0; m < 4; ++m) {
        *(uint2*)(pw + m * 16)     = make_uint2(acc[m][0], acc[m][1]);
        *(uint2*)(pw + m * 16 + 8) = make_uint2(acc[m][2], acc[m][3]);
    }
    __syncthreads();

    float in0 = 0.f, in1 = 0.f, in2 = 0.f, in3 = 0.f;
    #pragma unroll
    for (int qq = 0; qq < 4; ++qq) {
        const char* rp = Part + (size_t)(qq * 256 + s) * PSTR + q * 16;
        uint2 lo = *(const uint2*)rp;
        uint2 hi = *(const uint2*)(rp + 8);
        h2 p0 = u2h(lo.x), p1 = u2h(lo.y), p2 = u2h(hi.x), p3 = u2h(hi.y);
        in0 += (float)p0.x + (float)p0.y;
        in1 += (float)p1.x + (float)p1.y;
        in2 += (float)p2.x + (float)p2.y;
        in3 += (float)p3.x + (float)p3.y;
    }

    const int i  = bi * 64 + ty + 16 * q;
    const int j0 = bj * 64 + tx;

    const float sa  = rs[i];
    const float sb0 = rs[1024 + j0];
    const float sb1 = rs[1024 + j0 + 16];
    const float sb2 = rs[1024 + j0 + 32];
    const float sb3 = rs[1024 + j0 + 48];

    const float v0 = in0 / (sa + sb0 - in0);
    const float v1 = in1 / (sa + sb1 - in1);
    const float v2 = in2 / (sa + sb2 - in2);
    const float v3 = in3 / (sa + sb3 - in3);

    float* outT = out + (size_t)1024 * 1024;
    out[(size_t)i * 1024 + j0]      = v0;
    out[(size_t)i * 1024 + j0 + 16] = v1;
    out[(size_t)i * 1024 + j0 + 32] = v2;
    out[(size_t)i * 1024 + j0 + 48] = v3;
    outT[(size_t)j0        * 1024 + i] = v0;
    outT[(size_t)(j0 + 16) * 1024 + i] = v1;
    outT[(size_t)(j0 + 32) * 1024 + i] = v2;
    outT[(size_t)(j0 + 48) * 1024 + i] = v3;
}

extern "C" void kernel_launch(void* const* d_in, const int* in_sizes, int n_in,
                              void* d_out, int out_size, void* d_ws, size_t ws_size,
                              hipStream_t stream) {
    const float* x1 = (const float*)d_in[0];
    const float* x2 = (const float*)d_in[1];
    float* out = (float*)d_out;

    uint2* Ah = (uint2*)d_ws;                       // 512 KB
    uint2* Bh = Ah + (size_t)1024 * 64;             // 512 KB
    float* rs = (float*)(Bh + (size_t)1024 * 64);   // 2048 floats

    hipFuncSetAttribute((const void*)jaccard_main,
                        hipFuncAttributeMaxDynamicSharedMemorySize, LDSZ);

    prepass<<<512, 256, 0, stream>>>(x1, x2, Ah, Bh, rs);
    jaccard_main<<<dim3(16, 16), 1024, LDSZ, stream>>>(Ah, Bh, rs, out);
}